// Round 23
// baseline (93.007 us; speedup 1.0000x reference)
//
#include <hip/hip_runtime.h>

#define NB 8
#define NN 128
#define ND 64
#define NE 3
#define NH 256
#define NOUT 64

typedef short bf16x8_t __attribute__((ext_vector_type(8)));
typedef float f32x16_t __attribute__((ext_vector_type(16)));
typedef unsigned short ushort_t;

static __device__ __forceinline__ unsigned short f2bf(float f) {
    unsigned u = __float_as_uint(f);
    u += 0x7FFFu + ((u >> 16) & 1u);
    return (unsigned short)(u >> 16);
}
static __device__ __forceinline__ unsigned pk2bf(float a, float b) {
    return (unsigned)f2bf(a) | ((unsigned)f2bf(b) << 16);
}
static __device__ __forceinline__ float bflo(unsigned u) { return __uint_as_float(u << 16); }
static __device__ __forceinline__ float bfhi(unsigned u) { return __uint_as_float(u & 0xffff0000u); }

// A-frag gen: relu(P + Q) from two bf16-packed uint4s -> bf16x8
static __device__ __forceinline__ bf16x8_t a_gen(uint4 pv, uint4 qv) {
    union { uint4 u; bf16x8_t v; } r;
    r.u.x = pk2bf(fmaxf(bflo(pv.x) + bflo(qv.x), 0.f), fmaxf(bfhi(pv.x) + bfhi(qv.x), 0.f));
    r.u.y = pk2bf(fmaxf(bflo(pv.y) + bflo(qv.y), 0.f), fmaxf(bfhi(pv.y) + bfhi(qv.y), 0.f));
    r.u.z = pk2bf(fmaxf(bflo(pv.z) + bflo(qv.z), 0.f), fmaxf(bfhi(pv.z) + bfhi(qv.z), 0.f));
    r.u.w = pk2bf(fmaxf(bflo(pv.w) + bflo(qv.w), 0.f), fmaxf(bfhi(pv.w) + bfhi(qv.w), 0.f));
    return r.v;
}

// ============ Kernel 1: We2 32x32-frag pack (0..23) + P/Q bf16 (24..215) + edge pack (216..1239) ============
// We2p layout (ushorts): [((e*8 + ntg)*16 + kk)*512 + lane*8 + x]
//   = bf16(We2[e][k = kk*16 + (lane>>5)*8 + x][n = ntg*32 + (lane&31)])
#define IT 16
__global__ __launch_bounds__(256) void prep_kernel(
    const float* __restrict__ We2, const float* __restrict__ ns,
    const float* __restrict__ We1, const float* __restrict__ be1,
    const float* __restrict__ edges,
    ushort_t* __restrict__ We2p,
    ushort_t* __restrict__ P, ushort_t* __restrict__ Q,
    ushort_t* __restrict__ list_ws, int4* __restrict__ cnts_ws)
{
    const int t = threadIdx.x;
    const int blk = blockIdx.x;

    if (blk < 24) {             // ---- We2p 32x32-fragment pack ----
        __shared__ float slab[256][33];   // col slab We2[e][:, n0..n0+31]
        const int e = blk >> 3, ntg = blk & 7;
        const int n0 = ntg * 32;
#pragma unroll
        for (int it = 0; it < 32; it++) {
            const int idx = it * 256 + t;
            const int k = idx >> 5, col = idx & 31;
            slab[k][col] = We2[((size_t)e * NH + k) * NH + n0 + col];
        }
        __syncthreads();
        ushort_t* dst = We2p + ((size_t)e * 8 + ntg) * 8192;
#pragma unroll
        for (int it = 0; it < 32; it++) {
            const int idx = it * 256 + t;
            const int kk = idx >> 9;
            const int rem = idx & 511;
            const int ln = rem >> 3, x = rem & 7;
            const int k = kk * 16 + (ln >> 5) * 8 + x;
            dst[idx] = f2bf(slab[k][ln & 31]);
        }
        return;
    }
    if (blk < 216) {            // ---- P/Q precompute -> bf16 ----
        __shared__ float ns_lds[IT][ND];
        const int blk2 = blk - 24;
        const int itile = blk2 & 7;
        const int e = (blk2 >> 3) % NE;
        const int b = blk2 / 24;
        const int i0 = itile * IT;
        for (int x = t; x < IT * ND; x += 256)
            ns_lds[x / ND][x % ND] = ns[(size_t)(b * NN + i0 + x / ND) * ND + (x % ND)];
        __syncthreads();
        const int h = t;
        float accP[IT], accQ[IT];
        const float bias = be1[e * NH + h];
#pragma unroll
        for (int m = 0; m < IT; m++) { accP[m] = 0.f; accQ[m] = bias; }
        const float* W1 = We1 + (size_t)e * 2 * ND * NH + h;
        for (int d = 0; d < ND; d++) {
            const float w1 = W1[(size_t)d * NH];
            const float w2 = W1[(size_t)(ND + d) * NH];
#pragma unroll
            for (int m = 0; m < IT; m++) {
                accP[m] = fmaf(ns_lds[m][d], w1, accP[m]);
                accQ[m] = fmaf(ns_lds[m][d], w2, accQ[m]);
            }
        }
#pragma unroll
        for (int m = 0; m < IT; m++) {
            const size_t idx = ((size_t)((b * NE + e) * NN) + i0 + m) * NH + h;
            P[idx] = f2bf(accP[m]);
            Q[idx] = f2bf(accQ[m]);
        }
        return;
    }
    // ---- edge pack: per (b,j): bucketed source lists by edge type ----
    {
        __shared__ unsigned long long wm[2][NE];
        const int pb = blk - 216;
        const int b = pb >> 7, j = pb & 127;
        const int lane = t & 63, wave = t >> 6;
        int ecls = -1;
        if (t < 128) {
            const float4 ev = *(const float4*)(edges + ((size_t)(b * NN + t) * NN + j) * 4);
            ecls = ev.y > 0.5f ? 0 : (ev.z > 0.5f ? 1 : (ev.w > 0.5f ? 2 : -1));
#pragma unroll
            for (int ee = 0; ee < NE; ee++) {
                unsigned long long m = __ballot(ecls == ee);
                if (lane == 0) wm[wave][ee] = m;
            }
        }
        __syncthreads();
        const int c0 = __popcll(wm[0][0]) + __popcll(wm[1][0]);
        const int c1 = __popcll(wm[0][1]) + __popcll(wm[1][1]);
        const int c2 = __popcll(wm[0][2]) + __popcll(wm[1][2]);
        if (t < 128 && ecls >= 0) {
            const unsigned long long lower = (1ull << lane) - 1ull;
            int pos = __popcll(wm[wave][ecls] & lower);
            if (wave == 1) pos += __popcll(wm[0][ecls]);
            pos += (ecls > 0 ? c0 : 0) + (ecls > 1 ? c1 : 0);
            list_ws[(size_t)pb * NN + pos] = (ushort_t)t;
        }
        if (t == 0) { int4 cc; cc.x = c0; cc.y = c1; cc.z = c2; cc.w = 0; cnts_ws[pb] = cc; }
    }
}

// ============ Kernel 2: LDS-gather GEMM, 32x32x16 MFMA; block=(b, 8 j's, col-half) ============
// LDS: P bf16 swizzled 64KB | B-half 32x32-frag-packed 64KB | Q bf16 4KB
__global__ __launch_bounds__(1024) void gemm_kernel(
    const ushort_t* __restrict__ Pbf,
    const ushort_t* __restrict__ Qbf,
    const ushort_t* __restrict__ We2p,
    const float* __restrict__ be2,
    const ushort_t* __restrict__ list_ws,
    const int4* __restrict__ cnts_ws,
    float* __restrict__ aggr3)
{
    // grid: 256 = b(8) x jq(16) x nh(2); 16 waves = 8 j x 2 col-quarters
    const int blk = blockIdx.x;
    const int nh = blk & 1;
    const int jq = (blk >> 1) & 15;
    const int b  = blk >> 5;
    const int tid = threadIdx.x;
    const int lane = tid & 63;
    const int wave = tid >> 6;
    const int j  = jq * 8 + (wave >> 1);
    const int qd = wave & 1;
    const int hi = lane >> 5;          // 0 or 1: k-half within a frag
    const int l31 = lane & 31;

    __shared__ __align__(16) char Lds[135168];       // 132 KB
    ushort_t* Bp = (ushort_t*)(Lds + 65536);
    ushort_t* Ql = (ushort_t*)(Lds + 131072);

    for (int e = 0; e < NE; e++) {
        __syncthreads();   // previous e's readers done before restage
        {   // stage P[b,e] bf16 -> LDS, XOR-swizzled rows (coalesced src)
            const ushort_t* Ps = Pbf + (size_t)(b * NE + e) * NN * NH;
#pragma unroll
            for (int it = 0; it < 4; it++) {
                const int c = it * 1024 + tid;        // 16B chunk id, 4096 total
                const int row = c >> 5, c16 = c & 31;
                const uint4 v = *(const uint4*)(Ps + c * 8);
                *(uint4*)(Lds + row * 512 + ((c16 * 16) ^ ((row & 7) << 4))) = v;
            }
            // stage B half (linear, 32x32-frag-packed): 4 ntg x 16 kk x 1KB
            const ushort_t* Bs = We2p + ((size_t)e * 8 + nh * 4) * 8192;
#pragma unroll
            for (int it = 0; it < 4; it++) {
                const int o = (it * 1024 + tid) * 8;
                *(uint4*)&Bp[o] = *(const uint4*)&Bs[o];
            }
            // stage Q bf16 for the block's 8 j's (4KB)
            if (tid < 256) {
                const ushort_t* Qs = Qbf + (size_t)((b * NE + e) * NN + jq * 8) * NH + tid * 8;
                *(uint4*)(Ql + tid * 8) = *(const uint4*)Qs;
            }
        }
        __syncthreads();

        const int4 cc = cnts_ws[b * NN + j];
        const int ce = e == 0 ? cc.x : (e == 1 ? cc.y : cc.z);
        const int start = (e > 0 ? cc.x : 0) + (e > 1 ? cc.y : 0);
        const ushort_t* Lj = list_ws + (size_t)(b * NN + j) * NN + start;
        const ushort_t* Qj = Ql + (wave >> 1) * NH;

        float bb[2];
#pragma unroll
        for (int nt = 0; nt < 2; nt++)
            bb[nt] = be2[e * NH + nh * 128 + qd * 64 + nt * 32 + l31];

        float rsum[2] = {0.f, 0.f};

        if (ce > 0) {
            const int T = (ce + 31) >> 5;
            for (int tt = 0; tt < T; tt++) {
                int p = tt * 32 + l31;
                p = p < ce ? p : ce - 1;
                const int row = Lj[p];
                const int rbase = row * 512;
                const int sw = (row & 7) << 4;

                f32x16_t acc[2];
                const f32x16_t z16 = {0.f, 0.f, 0.f, 0.f, 0.f, 0.f, 0.f, 0.f,
                                      0.f, 0.f, 0.f, 0.f, 0.f, 0.f, 0.f, 0.f};
                acc[0] = z16; acc[1] = z16;

#pragma unroll 2
                for (int kk = 0; kk < 16; kk++) {
                    const int xo = kk * 32 + hi * 16;
                    const uint4 pv = *(const uint4*)(Lds + rbase + (xo ^ sw));
                    const uint4 qv = *(const uint4*)((const char*)Qj + xo);
                    const bf16x8_t af = a_gen(pv, qv);
#pragma unroll
                    for (int nt = 0; nt < 2; nt++) {
                        const bf16x8_t bfr = *(const bf16x8_t*)(&Bp[((qd * 2 + nt) * 16 + kk) * 512 + lane * 8]);
                        acc[nt] = __builtin_amdgcn_mfma_f32_32x32x16_bf16(af, bfr, acc[nt], 0, 0, 0);
                    }
                }
                // epilogue: bias+relu+row-mask, col sums (C/D: col=lane&31, row=(r&3)+8*(r>>2)+4*hi)
#pragma unroll
                for (int nt = 0; nt < 2; nt++) {
                    float s = 0.f;
#pragma unroll
                    for (int r = 0; r < 16; r++) {
                        const int pos = tt * 32 + (r & 3) + 8 * (r >> 2) + 4 * hi;
                        if (pos < ce) s += fmaxf(acc[nt][r] + bb[nt], 0.f);
                    }
                    s += __shfl_xor(s, 32, 64);
                    rsum[nt] += s;
                }
            }
        }
        // direct store (unique writer per (b,e,j,col); ce==0 writes zeros)
        if (lane < 32) {
            float* dst = aggr3 + (size_t)((b * NE + e) * NN + j) * NH + nh * 128 + qd * 64 + l31;
            dst[0] = rsum[0];
            dst[32] = rsum[1];
        }
    }
}

// ============ Kernel 3: decoder, 4 j's per block ============
__global__ __launch_bounds__(256) void dec_kernel(
    const float* __restrict__ ns,
    const float* __restrict__ aggr3,
    const float* __restrict__ Wd1, const float* __restrict__ bd1,
    const float* __restrict__ Wd2, const float* __restrict__ bd2,
    float* __restrict__ out)
{
    // grid: 256 = b(8) x jq(32); block handles j = jq*4 + 0..3
    const int b = blockIdx.x >> 5;
    const int jq = blockIdx.x & 31;
    const int tid = threadIdx.x;
    __shared__ __align__(16) float xs[4][320];
    __shared__ __align__(16) float o1s[4][NH];

    for (int x = tid; x < 4 * 320; x += 256) {
        const int jj = x / 320, k = x % 320;
        const int j = jq * 4 + jj;
        float v;
        if (k < ND) v = ns[(size_t)(b * NN + j) * ND + k];
        else {
            const int c = k - ND;
            v = aggr3[(size_t)((b * NE + 0) * NN + j) * NH + c]
              + aggr3[(size_t)((b * NE + 1) * NN + j) * NH + c]
              + aggr3[(size_t)((b * NE + 2) * NN + j) * NH + c];
        }
        xs[jj][k] = v;
    }
    __syncthreads();
    {
        const int n = tid;
        float acc[4];
        const float b1 = bd1[n];
#pragma unroll
        for (int jj = 0; jj < 4; jj++) acc[jj] = b1;
        for (int k4 = 0; k4 < 80; k4++) {
            const float w0 = Wd1[(size_t)(k4 * 4 + 0) * NH + n];
            const float w1 = Wd1[(size_t)(k4 * 4 + 1) * NH + n];
            const float w2 = Wd1[(size_t)(k4 * 4 + 2) * NH + n];
            const float w3 = Wd1[(size_t)(k4 * 4 + 3) * NH + n];
#pragma unroll
            for (int jj = 0; jj < 4; jj++) {
                const float4 xv = *(const float4*)(&xs[jj][k4 * 4]);
                acc[jj] = fmaf(xv.x, w0, fmaf(xv.y, w1, fmaf(xv.z, w2, fmaf(xv.w, w3, acc[jj]))));
            }
        }
#pragma unroll
        for (int jj = 0; jj < 4; jj++) o1s[jj][n] = fmaxf(acc[jj], 0.f);
    }
    __syncthreads();
    {
        const int jj = tid >> 6, col = tid & 63;
        float a = bd2[col];
        for (int h4 = 0; h4 < 64; h4++) {
            const float4 ov = *(const float4*)(&o1s[jj][h4 * 4]);
            a = fmaf(ov.x, Wd2[(size_t)(h4 * 4 + 0) * NOUT + col], a);
            a = fmaf(ov.y, Wd2[(size_t)(h4 * 4 + 1) * NOUT + col], a);
            a = fmaf(ov.z, Wd2[(size_t)(h4 * 4 + 2) * NOUT + col], a);
            a = fmaf(ov.w, Wd2[(size_t)(h4 * 4 + 3) * NOUT + col], a);
        }
        const int j = jq * 4 + jj;
        out[(size_t)(b * NN + j) * NOUT + col] = fmaxf(a, 0.f);
    }
}

extern "C" void kernel_launch(void* const* d_in, const int* in_sizes, int n_in,
                              void* d_out, int out_size, void* d_ws, size_t ws_size,
                              hipStream_t stream)
{
    const float* ns    = (const float*)d_in[0];
    const float* edges = (const float*)d_in[1];
    const float* We1   = (const float*)d_in[2];
    const float* be1   = (const float*)d_in[3];
    const float* We2   = (const float*)d_in[4];
    const float* be2   = (const float*)d_in[5];
    const float* Wd1   = (const float*)d_in[6];
    const float* bd1   = (const float*)d_in[7];
    const float* Wd2   = (const float*)d_in[8];
    const float* bd2   = (const float*)d_in[9];
    float* outp = (float*)d_out;

    // ws layout (~5.5 MB)
    ushort_t* Pbf = (ushort_t*)d_ws;                              // 786432 us
    ushort_t* Qbf = Pbf + (size_t)NB * NE * NN * NH;              // 786432 us
    ushort_t* We2p = Qbf + (size_t)NB * NE * NN * NH;             // 196608 us
    ushort_t* list_ws = We2p + (size_t)NE * NH * NH;              // 131072 us
    int4* cnts_ws = (int4*)(list_ws + (size_t)NB * NN * NN);      // 1024 int4
    float* aggr3 = (float*)(cnts_ws + NB * NN);                   // 786432 f32

    hipLaunchKernelGGL(prep_kernel, dim3(1240), dim3(256), 0, stream,
                       We2, ns, We1, be1, edges, We2p, Pbf, Qbf, list_ws, cnts_ws);
    hipLaunchKernelGGL(gemm_kernel, dim3(256), dim3(1024), 0, stream,
                       Pbf, Qbf, We2p, be2, list_ws, cnts_ws, aggr3);
    hipLaunchKernelGGL(dec_kernel, dim3(256), dim3(256), 0, stream,
                       ns, aggr3, Wd1, bd1, Wd2, bd2, outp);
}